// Round 1
// baseline (878.635 us; speedup 1.0000x reference)
//
#include <hip/hip_runtime.h>

#define N_USERS 100000
#define N_ITEMS 50000
#define N_NODES 150000
#define D 64
#define NNZ 2000000
#define BATCH 256
#define POP_BINS 10

#define NB_SCAN 586   // ceil(150000/256)

// ---------------- init: emb concat -> bufA, Oacc = 0.25*emb, zero counts ----
__global__ __launch_bounds__(256) void k_init(const float* __restrict__ ue,
                                              const float* __restrict__ ie,
                                              float* __restrict__ bufA,
                                              float* __restrict__ Oacc,
                                              int* __restrict__ counts) {
  int idx = blockIdx.x * 256 + threadIdx.x;
  if (idx < N_NODES * D) {
    float e = (idx < N_USERS * D) ? ue[idx] : ie[idx - N_USERS * D];
    bufA[idx] = e;
    Oacc[idx] = 0.25f * e;
  }
  if (idx < N_NODES) counts[idx] = 0;
}

// ---------------- CSR build ----------------
__global__ __launch_bounds__(256) void k_count(const int* __restrict__ rows,
                                               int* __restrict__ counts) {
  int e = blockIdx.x * 256 + threadIdx.x;
  if (e < NNZ) atomicAdd(&counts[rows[e]], 1);
}

__global__ __launch_bounds__(256) void k_scan1(const int* __restrict__ in,
                                               int* __restrict__ out,
                                               int* __restrict__ bsums, int n) {
  __shared__ int s[256];
  int t = threadIdx.x;
  int g = blockIdx.x * 256 + t;
  int v = (g < n) ? in[g] : 0;
  s[t] = v;
  __syncthreads();
  for (int off = 1; off < 256; off <<= 1) {
    int x = (t >= off) ? s[t - off] : 0;
    __syncthreads();
    s[t] += x;
    __syncthreads();
  }
  if (g < n) out[g] = s[t] - v;  // exclusive
  if (t == 255) bsums[blockIdx.x] = s[t];
}

__global__ __launch_bounds__(1024) void k_scan2(int* __restrict__ bs, int nb) {
  __shared__ int s[1024];
  int t = threadIdx.x;
  int v = (t < nb) ? bs[t] : 0;
  s[t] = v;
  __syncthreads();
  for (int off = 1; off < 1024; off <<= 1) {
    int x = (t >= off) ? s[t - off] : 0;
    __syncthreads();
    s[t] += x;
    __syncthreads();
  }
  if (t < nb) bs[t] = s[t] - v;  // exclusive
}

__global__ __launch_bounds__(256) void k_scan3(int* __restrict__ rowptr,
                                               int* __restrict__ cursor,
                                               const int* __restrict__ bsums, int n) {
  int g = blockIdx.x * 256 + threadIdx.x;
  if (g < n) {
    int v = rowptr[g] + bsums[blockIdx.x];
    rowptr[g] = v;
    cursor[g] = v;
  }
  if (g == 0) rowptr[n] = NNZ;
}

__global__ __launch_bounds__(256) void k_scatter(const int* __restrict__ rows,
                                                 const int* __restrict__ cols,
                                                 const float* __restrict__ vals,
                                                 int* __restrict__ cursor,
                                                 uint2* __restrict__ epack) {
  int e = blockIdx.x * 256 + threadIdx.x;
  if (e < NNZ) {
    int pos = atomicAdd(&cursor[rows[e]], 1);
    epack[pos] = make_uint2((unsigned)cols[e], __float_as_uint(vals[e]));
  }
}

// ---------------- SPMM: one wave per row, scalar edge loads ----------------
__global__ __launch_bounds__(256) void k_spmm(const int* __restrict__ rowptr,
                                              const uint2* __restrict__ epack,
                                              const float* __restrict__ Ein,
                                              float* __restrict__ Eout,
                                              float* __restrict__ Oacc) {
  int wave = blockIdx.x * 4 + (threadIdx.x >> 6);
  int row = __builtin_amdgcn_readfirstlane(wave);  // force uniform -> s_loads
  if (row >= N_NODES) return;
  int lane = threadIdx.x & 63;
  int beg = rowptr[row];
  int end = rowptr[row + 1];
  float acc0 = 0.f, acc1 = 0.f;
  int j = beg;
  for (; j + 3 < end; j += 4) {
    uint2 e0 = epack[j], e1 = epack[j + 1], e2 = epack[j + 2], e3 = epack[j + 3];
    acc0 += __uint_as_float(e0.y) * Ein[(int)e0.x * D + lane];
    acc1 += __uint_as_float(e1.y) * Ein[(int)e1.x * D + lane];
    acc0 += __uint_as_float(e2.y) * Ein[(int)e2.x * D + lane];
    acc1 += __uint_as_float(e3.y) * Ein[(int)e3.x * D + lane];
  }
  for (; j < end; ++j) {
    uint2 e0 = epack[j];
    acc0 += __uint_as_float(e0.y) * Ein[(int)e0.x * D + lane];
  }
  float acc = acc0 + acc1;
  int o = row * D + lane;
  Eout[o] = acc;
  Oacc[o] += 0.25f * acc;
}

// ---------------- weight transposes: gW1T[64][128], iW1T[64][64], uW1T[64][64]
__global__ __launch_bounds__(256) void k_wt(const float* __restrict__ gW1,
                                            const float* __restrict__ iW1,
                                            const float* __restrict__ uW1,
                                            float* __restrict__ WT) {
  int t = blockIdx.x * 256 + threadIdx.x;
  if (t < 8192) {
    int o = t >> 7, k = t & 127;
    WT[t] = gW1[k * 64 + o];
  } else if (t < 12288) {
    int q = t - 8192;
    int o = q >> 6, k = q & 63;
    WT[t] = iW1[k * 64 + o];
  } else if (t < 16384) {
    int q = t - 12288;
    int o = q >> 6, k = q & 63;
    WT[t] = uW1[k * 64 + o];
  }
}

// ---------------- user MLP: thread per user, scalar weights, write U^T ------
__global__ __launch_bounds__(64) void k_user(const float* __restrict__ Oacc,
                                             const int* __restrict__ users,
                                             const float* __restrict__ ubias,
                                             const float* __restrict__ uW1T,
                                             const float* __restrict__ ub1,
                                             const float* __restrict__ uW2,
                                             const float* __restrict__ ub2,
                                             float* __restrict__ Ut) {
  int b = blockIdx.x * 64 + threadIdx.x;
  int u = users[b];
  float x[64];
  const float4* xr = (const float4*)(Oacc + (size_t)u * 64);
#pragma unroll
  for (int q = 0; q < 16; q++) {
    float4 t4 = xr[q];
    x[4 * q] = t4.x; x[4 * q + 1] = t4.y; x[4 * q + 2] = t4.z; x[4 * q + 3] = t4.w;
  }
  float acc[64];
#pragma unroll
  for (int o2 = 0; o2 < 64; o2++) acc[o2] = ub2[o2];
#pragma unroll 1
  for (int o = 0; o < 64; o++) {
    const float* w = uW1T + o * 64;
    float a0 = ub1[o], a1 = 0.f, a2 = 0.f, a3 = 0.f;
#pragma unroll
    for (int k = 0; k < 64; k += 4) {
      a0 += x[k] * w[k]; a1 += x[k + 1] * w[k + 1];
      a2 += x[k + 2] * w[k + 2]; a3 += x[k + 3] * w[k + 3];
    }
    float hv = a0 + a1 + a2 + a3;
    hv = hv > 0.f ? hv : 0.f;
    const float* w2 = uW2 + o * 64;
#pragma unroll
    for (int o2 = 0; o2 < 64; o2++) acc[o2] += hv * w2[o2];
  }
#pragma unroll 1
  for (int o2 = 0; o2 < 64; o2++) Ut[o2 * 256 + b] = acc[o2];
  Ut[64 * 256 + b] = ubias[u];  // BIAS_SCALE = 1.0
}

// ---------------- gate + item MLP fused: thread per item --------------------
__global__ __launch_bounds__(256) void k_gate(const float* __restrict__ Oacc,
                                              const float* __restrict__ pop,
                                              const int* __restrict__ bins,
                                              const float* __restrict__ gW1T,
                                              const float* __restrict__ gb1,
                                              const float* __restrict__ gW2,
                                              const float* __restrict__ gb2,
                                              const float* __restrict__ iW1T,
                                              const float* __restrict__ ib1,
                                              const float* __restrict__ iW2,
                                              const float* __restrict__ ib2,
                                              float* __restrict__ I) {
  __shared__ float Xs[256 * 65];
  int i0 = blockIdx.x * 256;
  int tid = threadIdx.x;
  for (int idx = tid; idx < 256 * 64; idx += 256) {
    int r = idx >> 6, c = idx & 63;
    Xs[r * 65 + c] = (i0 + r < N_ITEMS) ? Oacc[(size_t)(N_USERS + i0 + r) * 64 + c] : 0.f;
  }
  __syncthreads();
  int i = i0 + tid;
  int bin = (i < N_ITEMS) ? bins[i] : 0;
  float x[64], p[64];
#pragma unroll
  for (int k = 0; k < 64; k++) x[k] = Xs[tid * 65 + k];
#pragma unroll
  for (int k = 0; k < 64; k++) p[k] = pop[bin * 64 + k];
  // gate: z = sigmoid(relu([x,p]@gW1+gb1)@gW2+gb2)
  float s = gb2[0];
#pragma unroll 1
  for (int o = 0; o < 64; o++) {
    const float* w = gW1T + o * 128;
    float a0 = gb1[o], a1 = 0.f, a2 = 0.f, a3 = 0.f;
#pragma unroll
    for (int k = 0; k < 64; k += 4) {
      a0 += x[k] * w[k]; a1 += x[k + 1] * w[k + 1];
      a2 += x[k + 2] * w[k + 2]; a3 += x[k + 3] * w[k + 3];
    }
#pragma unroll
    for (int k = 0; k < 64; k += 4) {
      a0 += p[k] * w[64 + k]; a1 += p[k + 1] * w[64 + k + 1];
      a2 += p[k + 2] * w[64 + k + 2]; a3 += p[k + 3] * w[64 + k + 3];
    }
    float hv = a0 + a1 + a2 + a3;
    hv = hv > 0.f ? hv : 0.f;
    s += hv * gW2[o];
  }
  float z = 1.f / (1.f + expf(-s));
#pragma unroll
  for (int k = 0; k < 64; k++) x[k] = (1.f - z) * x[k] + z * p[k];
  // item MLP
  float acc[64];
#pragma unroll
  for (int o2 = 0; o2 < 64; o2++) acc[o2] = ib2[o2];
#pragma unroll 1
  for (int o = 0; o < 64; o++) {
    const float* w = iW1T + o * 64;
    float a0 = ib1[o], a1 = 0.f, a2 = 0.f, a3 = 0.f;
#pragma unroll
    for (int k = 0; k < 64; k += 4) {
      a0 += x[k] * w[k]; a1 += x[k + 1] * w[k + 1];
      a2 += x[k + 2] * w[k + 2]; a3 += x[k + 3] * w[k + 3];
    }
    float hv = a0 + a1 + a2 + a3;
    hv = hv > 0.f ? hv : 0.f;
    const float* w2 = iW2 + o * 64;
#pragma unroll
    for (int o2 = 0; o2 < 64; o2++) acc[o2] += hv * w2[o2];
  }
#pragma unroll
  for (int o2 = 0; o2 < 64; o2++) Xs[tid * 65 + o2] = acc[o2];
  __syncthreads();
  for (int idx = tid; idx < 256 * 64; idx += 256) {
    int r = idx >> 6, c = idx & 63;
    if (i0 + r < N_ITEMS) I[(size_t)(i0 + r) * 64 + c] = Xs[r * 65 + c];
  }
}

// ---------------- scores: thread per item, 8-user accumulator tiles ---------
__global__ __launch_bounds__(256) void k_scores(const float* __restrict__ I,
                                                const float* __restrict__ Ut,
                                                const float* __restrict__ item_bias,
                                                float* __restrict__ out) {
  __shared__ float Is[256 * 65];
  int i0 = blockIdx.x * 256;
  int tid = threadIdx.x;
  for (int idx = tid; idx < 256 * 64; idx += 256) {
    int r = idx >> 6, c = idx & 63;
    Is[r * 65 + c] = (i0 + r < N_ITEMS) ? I[(size_t)(i0 + r) * 64 + c] : 0.f;
  }
  __syncthreads();
  int i = i0 + tid;
  bool valid = i < N_ITEMS;
  float ib = valid ? item_bias[i] : 0.f;
  float xr[64];
#pragma unroll
  for (int k = 0; k < 64; k++) xr[k] = Is[tid * 65 + k];
  int bbase = blockIdx.y * 128;
#pragma unroll 1
  for (int b0 = 0; b0 < 128; b0 += 8) {
    float acc[8];
#pragma unroll
    for (int jj = 0; jj < 8; jj++) acc[jj] = 0.f;
#pragma unroll
    for (int k = 0; k < 64; k++) {
      float iv = xr[k];
      const float* urow = Ut + k * 256 + bbase + b0;
#pragma unroll
      for (int jj = 0; jj < 8; jj++) acc[jj] += iv * urow[jj];
    }
    if (valid) {
#pragma unroll
      for (int jj = 0; jj < 8; jj++) {
        int b = bbase + b0 + jj;
        out[b * N_ITEMS + i] = acc[jj] + Ut[64 * 256 + b] + ib;
      }
    }
  }
}

extern "C" void kernel_launch(void* const* d_in, const int* in_sizes, int n_in,
                              void* d_out, int out_size, void* d_ws, size_t ws_size,
                              hipStream_t stream) {
  const float* user_emb  = (const float*)d_in[0];
  const float* item_emb  = (const float*)d_in[1];
  const float* user_bias = (const float*)d_in[2];
  const float* item_bias = (const float*)d_in[3];
  const float* pop_emb   = (const float*)d_in[4];
  const float* uW1 = (const float*)d_in[5];
  const float* ub1 = (const float*)d_in[6];
  const float* uW2 = (const float*)d_in[7];
  const float* ub2 = (const float*)d_in[8];
  const float* iW1 = (const float*)d_in[9];
  const float* ib1 = (const float*)d_in[10];
  const float* iW2 = (const float*)d_in[11];
  const float* ib2 = (const float*)d_in[12];
  const float* gW1 = (const float*)d_in[13];
  const float* gb1 = (const float*)d_in[14];
  const float* gW2 = (const float*)d_in[15];
  const float* gb2 = (const float*)d_in[16];
  const float* adj_vals = (const float*)d_in[17];
  const int* adj_rows = (const int*)d_in[18];
  const int* adj_cols = (const int*)d_in[19];
  const int* bins  = (const int*)d_in[20];
  const int* users = (const int*)d_in[21];
  float* out = (float*)d_out;

  // workspace layout (float offsets); total ~132.7 MB
  float* ws = (float*)d_ws;
  float* Oacc = ws;                    // 9,600,000
  float* bufA = ws + 9600000;          // 9,600,000
  float* bufB = ws + 19200000;         // 9,600,000
  uint2* epack = (uint2*)(ws + 28800000);      // 2,000,000 * 8B
  int* rowptr = (int*)(ws + 32800000);         // 150,001
  int* cursor = (int*)(ws + 32960000);         // 150,000
  int* bsums  = (int*)(ws + 33120000);         // 1,024
  float* Ut   = ws + 33130000;                 // 65*256
  float* WT   = ws + 33150000;                 // 16,384
  const float* gW1T = WT;
  const float* iW1T = WT + 8192;
  const float* uW1T = WT + 12288;

  k_init<<<37500, 256, 0, stream>>>(user_emb, item_emb, bufA, Oacc, cursor);
  k_count<<<(NNZ + 255) / 256, 256, 0, stream>>>(adj_rows, cursor);
  k_scan1<<<NB_SCAN, 256, 0, stream>>>(cursor, rowptr, bsums, N_NODES);
  k_scan2<<<1, 1024, 0, stream>>>(bsums, NB_SCAN);
  k_scan3<<<NB_SCAN, 256, 0, stream>>>(rowptr, cursor, bsums, N_NODES);
  k_scatter<<<(NNZ + 255) / 256, 256, 0, stream>>>(adj_rows, adj_cols, adj_vals, cursor, epack);

  k_spmm<<<37500, 256, 0, stream>>>(rowptr, epack, bufA, bufB, Oacc);
  k_spmm<<<37500, 256, 0, stream>>>(rowptr, epack, bufB, bufA, Oacc);
  k_spmm<<<37500, 256, 0, stream>>>(rowptr, epack, bufA, bufB, Oacc);

  k_wt<<<64, 256, 0, stream>>>(gW1, iW1, uW1, WT);
  k_user<<<4, 64, 0, stream>>>(Oacc, users, user_bias, uW1T, ub1, uW2, ub2, Ut);
  k_gate<<<196, 256, 0, stream>>>(Oacc, pop_emb, bins, gW1T, gb1, gW2, gb2,
                                  iW1T, ib1, iW2, ib2, bufA);
  k_scores<<<dim3(196, 2), 256, 0, stream>>>(bufA, Ut, item_bias, out);
}

// Round 2
// 844.124 us; speedup vs baseline: 1.0409x; 1.0409x over previous
//
#include <hip/hip_runtime.h>

#define N_USERS 100000
#define N_ITEMS 50000
#define N_NODES 150000
#define D 64
#define NNZ 2000000
#define BATCH 256
#define POP_BINS 10

#define NB_SCAN 586   // ceil(150000/256)

// bucketed scatter params
#define BSHIFT 10
#define NBUCK 147          // ceil(150000/1024)
#define P1_EPB 4096        // edges per block in pass 1
#define P1_BLOCKS 489      // ceil(NNZ/P1_EPB)

// ---------------- init: emb concat -> bufA, Oacc = 0.25*emb, zero counts ----
__global__ __launch_bounds__(256) void k_init(const float* __restrict__ ue,
                                              const float* __restrict__ ie,
                                              float* __restrict__ bufA,
                                              float* __restrict__ Oacc,
                                              int* __restrict__ counts) {
  int idx = blockIdx.x * 256 + threadIdx.x;
  if (idx < N_NODES * D) {
    float e = (idx < N_USERS * D) ? ue[idx] : ie[idx - N_USERS * D];
    bufA[idx] = e;
    Oacc[idx] = 0.25f * e;
  }
  if (idx < N_NODES) counts[idx] = 0;
}

// ---------------- CSR build ----------------
__global__ __launch_bounds__(256) void k_count(const int* __restrict__ rows,
                                               int* __restrict__ counts) {
  int e = blockIdx.x * 256 + threadIdx.x;
  if (e < NNZ) atomicAdd(&counts[rows[e]], 1);
}

__global__ __launch_bounds__(256) void k_scan1(const int* __restrict__ in,
                                               int* __restrict__ out,
                                               int* __restrict__ bsums, int n) {
  __shared__ int s[256];
  int t = threadIdx.x;
  int g = blockIdx.x * 256 + t;
  int v = (g < n) ? in[g] : 0;
  s[t] = v;
  __syncthreads();
  for (int off = 1; off < 256; off <<= 1) {
    int x = (t >= off) ? s[t - off] : 0;
    __syncthreads();
    s[t] += x;
    __syncthreads();
  }
  if (g < n) out[g] = s[t] - v;  // exclusive
  if (t == 255) bsums[blockIdx.x] = s[t];
}

__global__ __launch_bounds__(1024) void k_scan2(int* __restrict__ bs, int nb) {
  __shared__ int s[1024];
  int t = threadIdx.x;
  int v = (t < nb) ? bs[t] : 0;
  s[t] = v;
  __syncthreads();
  for (int off = 1; off < 1024; off <<= 1) {
    int x = (t >= off) ? s[t - off] : 0;
    __syncthreads();
    s[t] += x;
    __syncthreads();
  }
  if (t < nb) bs[t] = s[t] - v;  // exclusive
}

__global__ __launch_bounds__(256) void k_scan3(int* __restrict__ rowptr,
                                               int* __restrict__ cursor,
                                               const int* __restrict__ bsums, int n) {
  int g = blockIdx.x * 256 + threadIdx.x;
  if (g < n) {
    int v = rowptr[g] + bsums[blockIdx.x];
    rowptr[g] = v;
    cursor[g] = v;
  }
  if (g == 0) rowptr[n] = NNZ;
}

__global__ __launch_bounds__(256) void k_binit(const int* __restrict__ rowptr,
                                               int* __restrict__ bcur) {
  int t = threadIdx.x;
  if (t < NBUCK) bcur[t] = rowptr[t << BSHIFT];
}

// ---------------- pass 1: bucket edges into staging (clustered writes) ------
__global__ __launch_bounds__(256) void k_p1(const int* __restrict__ rows,
                                            const int* __restrict__ cols,
                                            const float* __restrict__ vals,
                                            int* __restrict__ bcur,
                                            uint2* __restrict__ gstage) {
  __shared__ int cnt[NBUCK];
  __shared__ int gbase[NBUCK];
  int t = threadIdx.x;
  if (t < NBUCK) cnt[t] = 0;
  __syncthreads();
  int base = blockIdx.x * P1_EPB;
  unsigned key[16]; float val[16]; int meta[16];
#pragma unroll
  for (int i = 0; i < 16; i++) {
    int e = base + i * 256 + t;
    meta[i] = -1;
    if (e < NNZ) {
      int r = rows[e];
      int b = r >> BSHIFT;
      int lr = r - (b << BSHIFT);
      key[i] = ((unsigned)lr << 18) | (unsigned)cols[e];
      val[i] = vals[e];
      int rank = atomicAdd(&cnt[b], 1);
      meta[i] = (b << 13) | rank;   // rank < 4096 fits in 13 bits
    }
  }
  __syncthreads();
  if (t < NBUCK) gbase[t] = atomicAdd(&bcur[t], cnt[t]);
  __syncthreads();
#pragma unroll
  for (int i = 0; i < 16; i++) {
    if (meta[i] >= 0) {
      int b = meta[i] >> 13, rank = meta[i] & 8191;
      gstage[gbase[b] + rank] = make_uint2(key[i], __float_as_uint(val[i]));
    }
  }
}

// ---------------- pass 2: bucket-local scatter to CSR position --------------
__global__ __launch_bounds__(256) void k_p2(const int* __restrict__ rowptr,
                                            const uint2* __restrict__ gstage,
                                            int* __restrict__ cursor,
                                            uint2* __restrict__ epack) {
  int b = blockIdx.x;
  int s = rowptr[b << BSHIFT];
  int rend = (b + 1) << BSHIFT;
  if (rend > N_NODES) rend = N_NODES;
  int e = rowptr[rend];
  int half = (e - s) >> 1;
  int lo = blockIdx.y ? (s + half) : s;
  int hi = blockIdx.y ? e : (s + half);
  int rowbase = b << BSHIFT;
  for (int j = lo + threadIdx.x; j < hi; j += 256) {
    uint2 ed = gstage[j];
    int row = rowbase + (int)(ed.x >> 18);
    int col = (int)(ed.x & 0x3FFFFu);
    int pos = atomicAdd(&cursor[row], 1);
    epack[pos] = make_uint2((unsigned)col, ed.y);
  }
}

// ---------------- SPMM: one wave per row, scalar edge loads ----------------
__global__ __launch_bounds__(256) void k_spmm(const int* __restrict__ rowptr,
                                              const uint2* __restrict__ epack,
                                              const float* __restrict__ Ein,
                                              float* __restrict__ Eout,
                                              float* __restrict__ Oacc) {
  int wave = blockIdx.x * 4 + (threadIdx.x >> 6);
  int row = __builtin_amdgcn_readfirstlane(wave);  // force uniform -> s_loads
  if (row >= N_NODES) return;
  int lane = threadIdx.x & 63;
  int beg = rowptr[row];
  int end = rowptr[row + 1];
  float acc0 = 0.f, acc1 = 0.f;
  int j = beg;
  for (; j + 3 < end; j += 4) {
    uint2 e0 = epack[j], e1 = epack[j + 1], e2 = epack[j + 2], e3 = epack[j + 3];
    acc0 += __uint_as_float(e0.y) * Ein[(int)e0.x * D + lane];
    acc1 += __uint_as_float(e1.y) * Ein[(int)e1.x * D + lane];
    acc0 += __uint_as_float(e2.y) * Ein[(int)e2.x * D + lane];
    acc1 += __uint_as_float(e3.y) * Ein[(int)e3.x * D + lane];
  }
  for (; j < end; ++j) {
    uint2 e0 = epack[j];
    acc0 += __uint_as_float(e0.y) * Ein[(int)e0.x * D + lane];
  }
  float acc = acc0 + acc1;
  int o = row * D + lane;
  Eout[o] = acc;
  Oacc[o] += 0.25f * acc;
}

// ---------------- weight transposes: gW1T[64][128], iW1T[64][64], uW1T[64][64]
__global__ __launch_bounds__(256) void k_wt(const float* __restrict__ gW1,
                                            const float* __restrict__ iW1,
                                            const float* __restrict__ uW1,
                                            float* __restrict__ WT) {
  int t = blockIdx.x * 256 + threadIdx.x;
  if (t < 8192) {
    int o = t >> 7, k = t & 127;
    WT[t] = gW1[k * 64 + o];
  } else if (t < 12288) {
    int q = t - 8192;
    int o = q >> 6, k = q & 63;
    WT[t] = iW1[k * 64 + o];
  } else if (t < 16384) {
    int q = t - 12288;
    int o = q >> 6, k = q & 63;
    WT[t] = uW1[k * 64 + o];
  }
}

// ---------------- user MLP: thread per user, scalar weights, write U^T ------
__global__ __launch_bounds__(64) void k_user(const float* __restrict__ Oacc,
                                             const int* __restrict__ users,
                                             const float* __restrict__ ubias,
                                             const float* __restrict__ uW1T,
                                             const float* __restrict__ ub1,
                                             const float* __restrict__ uW2,
                                             const float* __restrict__ ub2,
                                             float* __restrict__ Ut) {
  int b = blockIdx.x * 64 + threadIdx.x;
  int u = users[b];
  float x[64];
  const float4* xr = (const float4*)(Oacc + (size_t)u * 64);
#pragma unroll
  for (int q = 0; q < 16; q++) {
    float4 t4 = xr[q];
    x[4 * q] = t4.x; x[4 * q + 1] = t4.y; x[4 * q + 2] = t4.z; x[4 * q + 3] = t4.w;
  }
  float acc[64];
#pragma unroll
  for (int o2 = 0; o2 < 64; o2++) acc[o2] = ub2[o2];
#pragma unroll 1
  for (int o = 0; o < 64; o++) {
    const float* w = uW1T + o * 64;
    float a0 = ub1[o], a1 = 0.f, a2 = 0.f, a3 = 0.f;
#pragma unroll
    for (int k = 0; k < 64; k += 4) {
      a0 += x[k] * w[k]; a1 += x[k + 1] * w[k + 1];
      a2 += x[k + 2] * w[k + 2]; a3 += x[k + 3] * w[k + 3];
    }
    float hv = a0 + a1 + a2 + a3;
    hv = hv > 0.f ? hv : 0.f;
    const float* w2 = uW2 + o * 64;
#pragma unroll
    for (int o2 = 0; o2 < 64; o2++) acc[o2] += hv * w2[o2];
  }
#pragma unroll 1
  for (int o2 = 0; o2 < 64; o2++) Ut[o2 * 256 + b] = acc[o2];
  Ut[64 * 256 + b] = ubias[u];  // BIAS_SCALE = 1.0
}

// ---------------- gate + item MLP fused: thread per item --------------------
__global__ __launch_bounds__(256) void k_gate(const float* __restrict__ Oacc,
                                              const float* __restrict__ pop,
                                              const int* __restrict__ bins,
                                              const float* __restrict__ gW1T,
                                              const float* __restrict__ gb1,
                                              const float* __restrict__ gW2,
                                              const float* __restrict__ gb2,
                                              const float* __restrict__ iW1T,
                                              const float* __restrict__ ib1,
                                              const float* __restrict__ iW2,
                                              const float* __restrict__ ib2,
                                              float* __restrict__ I) {
  __shared__ float Xs[256 * 65];
  int i0 = blockIdx.x * 256;
  int tid = threadIdx.x;
  for (int idx = tid; idx < 256 * 64; idx += 256) {
    int r = idx >> 6, c = idx & 63;
    Xs[r * 65 + c] = (i0 + r < N_ITEMS) ? Oacc[(size_t)(N_USERS + i0 + r) * 64 + c] : 0.f;
  }
  __syncthreads();
  int i = i0 + tid;
  int bin = (i < N_ITEMS) ? bins[i] : 0;
  float x[64], p[64];
#pragma unroll
  for (int k = 0; k < 64; k++) x[k] = Xs[tid * 65 + k];
#pragma unroll
  for (int k = 0; k < 64; k++) p[k] = pop[bin * 64 + k];
  // gate: z = sigmoid(relu([x,p]@gW1+gb1)@gW2+gb2)
  float s = gb2[0];
#pragma unroll 1
  for (int o = 0; o < 64; o++) {
    const float* w = gW1T + o * 128;
    float a0 = gb1[o], a1 = 0.f, a2 = 0.f, a3 = 0.f;
#pragma unroll
    for (int k = 0; k < 64; k += 4) {
      a0 += x[k] * w[k]; a1 += x[k + 1] * w[k + 1];
      a2 += x[k + 2] * w[k + 2]; a3 += x[k + 3] * w[k + 3];
    }
#pragma unroll
    for (int k = 0; k < 64; k += 4) {
      a0 += p[k] * w[64 + k]; a1 += p[k + 1] * w[64 + k + 1];
      a2 += p[k + 2] * w[64 + k + 2]; a3 += p[k + 3] * w[64 + k + 3];
    }
    float hv = a0 + a1 + a2 + a3;
    hv = hv > 0.f ? hv : 0.f;
    s += hv * gW2[o];
  }
  float z = 1.f / (1.f + expf(-s));
#pragma unroll
  for (int k = 0; k < 64; k++) x[k] = (1.f - z) * x[k] + z * p[k];
  // item MLP
  float acc[64];
#pragma unroll
  for (int o2 = 0; o2 < 64; o2++) acc[o2] = ib2[o2];
#pragma unroll 1
  for (int o = 0; o < 64; o++) {
    const float* w = iW1T + o * 64;
    float a0 = ib1[o], a1 = 0.f, a2 = 0.f, a3 = 0.f;
#pragma unroll
    for (int k = 0; k < 64; k += 4) {
      a0 += x[k] * w[k]; a1 += x[k + 1] * w[k + 1];
      a2 += x[k + 2] * w[k + 2]; a3 += x[k + 3] * w[k + 3];
    }
    float hv = a0 + a1 + a2 + a3;
    hv = hv > 0.f ? hv : 0.f;
    const float* w2 = iW2 + o * 64;
#pragma unroll
    for (int o2 = 0; o2 < 64; o2++) acc[o2] += hv * w2[o2];
  }
#pragma unroll
  for (int o2 = 0; o2 < 64; o2++) Xs[tid * 65 + o2] = acc[o2];
  __syncthreads();
  for (int idx = tid; idx < 256 * 64; idx += 256) {
    int r = idx >> 6, c = idx & 63;
    if (i0 + r < N_ITEMS) I[(size_t)(i0 + r) * 64 + c] = Xs[r * 65 + c];
  }
}

// ---------------- scores: thread per item, 8-user accumulator tiles ---------
__global__ __launch_bounds__(256) void k_scores(const float* __restrict__ I,
                                                const float* __restrict__ Ut,
                                                const float* __restrict__ item_bias,
                                                float* __restrict__ out) {
  __shared__ float Is[256 * 65];
  int i0 = blockIdx.x * 256;
  int tid = threadIdx.x;
  for (int idx = tid; idx < 256 * 64; idx += 256) {
    int r = idx >> 6, c = idx & 63;
    Is[r * 65 + c] = (i0 + r < N_ITEMS) ? I[(size_t)(i0 + r) * 64 + c] : 0.f;
  }
  __syncthreads();
  int i = i0 + tid;
  bool valid = i < N_ITEMS;
  float ib = valid ? item_bias[i] : 0.f;
  float xr[64];
#pragma unroll
  for (int k = 0; k < 64; k++) xr[k] = Is[tid * 65 + k];
  int bbase = blockIdx.y * 128;
#pragma unroll 1
  for (int b0 = 0; b0 < 128; b0 += 8) {
    float acc[8];
#pragma unroll
    for (int jj = 0; jj < 8; jj++) acc[jj] = 0.f;
#pragma unroll
    for (int k = 0; k < 64; k++) {
      float iv = xr[k];
      const float* urow = Ut + k * 256 + bbase + b0;
#pragma unroll
      for (int jj = 0; jj < 8; jj++) acc[jj] += iv * urow[jj];
    }
    if (valid) {
#pragma unroll
      for (int jj = 0; jj < 8; jj++) {
        int b = bbase + b0 + jj;
        out[b * N_ITEMS + i] = acc[jj] + Ut[64 * 256 + b] + ib;
      }
    }
  }
}

extern "C" void kernel_launch(void* const* d_in, const int* in_sizes, int n_in,
                              void* d_out, int out_size, void* d_ws, size_t ws_size,
                              hipStream_t stream) {
  const float* user_emb  = (const float*)d_in[0];
  const float* item_emb  = (const float*)d_in[1];
  const float* user_bias = (const float*)d_in[2];
  const float* item_bias = (const float*)d_in[3];
  const float* pop_emb   = (const float*)d_in[4];
  const float* uW1 = (const float*)d_in[5];
  const float* ub1 = (const float*)d_in[6];
  const float* uW2 = (const float*)d_in[7];
  const float* ub2 = (const float*)d_in[8];
  const float* iW1 = (const float*)d_in[9];
  const float* ib1 = (const float*)d_in[10];
  const float* iW2 = (const float*)d_in[11];
  const float* ib2 = (const float*)d_in[12];
  const float* gW1 = (const float*)d_in[13];
  const float* gb1 = (const float*)d_in[14];
  const float* gW2 = (const float*)d_in[15];
  const float* gb2 = (const float*)d_in[16];
  const float* adj_vals = (const float*)d_in[17];
  const int* adj_rows = (const int*)d_in[18];
  const int* adj_cols = (const int*)d_in[19];
  const int* bins  = (const int*)d_in[20];
  const int* users = (const int*)d_in[21];
  float* out = (float*)d_out;

  // workspace layout (float offsets); total ~132.7 MB
  float* ws = (float*)d_ws;
  float* Oacc = ws;                    // 9,600,000
  float* bufA = ws + 9600000;          // 9,600,000
  float* bufB = ws + 19200000;         // 9,600,000 (gstage aliases this pre-SPMM)
  uint2* epack = (uint2*)(ws + 28800000);      // 2,000,000 * 8B
  int* rowptr = (int*)(ws + 32800000);         // 150,001
  int* cursor = (int*)(ws + 32960000);         // 150,000
  int* bsums  = (int*)(ws + 33120000);         // 1,024
  float* Ut   = ws + 33130000;                 // 65*256
  float* WT   = ws + 33150000;                 // 16,384
  int* bcur   = (int*)(ws + 33170000);         // 147
  uint2* gstage = (uint2*)bufB;                // 2,000,000 * 8B, dead before SPMM L1
  const float* gW1T = WT;
  const float* iW1T = WT + 8192;
  const float* uW1T = WT + 12288;

  k_init<<<37500, 256, 0, stream>>>(user_emb, item_emb, bufA, Oacc, cursor);
  k_count<<<(NNZ + 255) / 256, 256, 0, stream>>>(adj_rows, cursor);
  k_scan1<<<NB_SCAN, 256, 0, stream>>>(cursor, rowptr, bsums, N_NODES);
  k_scan2<<<1, 1024, 0, stream>>>(bsums, NB_SCAN);
  k_scan3<<<NB_SCAN, 256, 0, stream>>>(rowptr, cursor, bsums, N_NODES);
  k_binit<<<1, 256, 0, stream>>>(rowptr, bcur);
  k_p1<<<P1_BLOCKS, 256, 0, stream>>>(adj_rows, adj_cols, adj_vals, bcur, gstage);
  k_p2<<<dim3(NBUCK, 2), 256, 0, stream>>>(rowptr, gstage, cursor, epack);

  k_spmm<<<37500, 256, 0, stream>>>(rowptr, epack, bufA, bufB, Oacc);
  k_spmm<<<37500, 256, 0, stream>>>(rowptr, epack, bufB, bufA, Oacc);
  k_spmm<<<37500, 256, 0, stream>>>(rowptr, epack, bufA, bufB, Oacc);

  k_wt<<<64, 256, 0, stream>>>(gW1, iW1, uW1, WT);
  k_user<<<4, 64, 0, stream>>>(Oacc, users, user_bias, uW1T, ub1, uW2, ub2, Ut);
  k_gate<<<196, 256, 0, stream>>>(Oacc, pop_emb, bins, gW1T, gb1, gW2, gb2,
                                  iW1T, ib1, iW2, ib2, bufA);
  k_scores<<<dim3(196, 2), 256, 0, stream>>>(bufA, Ut, item_bias, out);
}